// Round 4
// baseline (267.518 us; speedup 1.0000x reference)
//
#include <hip/hip_runtime.h>
#include <hip/hip_bf16.h>
#include <stdint.h>

// BSpline KAN layer: out[b,o] = sum_{i,k} bases(tanh(x[b,i]))[k] * C[i,o,k]
// == GEMM M=8192, N=512, K=4096 with generated A. bf16 MFMA path.
// R4: R2's 64x32 wave partition (B non-duplicated) + R3's verified 0-conflict
// XOR swizzle + BK=128 (32 barriers) + strict cross-phase prefetch (x two
// phases ahead, B one phase ahead) + 1/6 folded into C + packed bf16 cvt.

typedef short s16x8 __attribute__((ext_vector_type(8)));   // 8 bf16
typedef float f32x4 __attribute__((ext_vector_type(4)));

#define BATCH 8192
#define IN_F  512
#define OUT_F 512
#define NB    8
#define CHUNK (OUT_F * 64)   // ushorts per 8-i block of BtT (64 KB)

#define BM  64
#define BN  128
#define BKI 16               // i's per phase (128 kk)
#define NPH (IN_F / BKI)     // 32 phases
#define LROW 256             // ushorts per LDS A row (512 B, 16 chunks of 16 B)

__device__ __forceinline__ uint32_t pk2(float a, float b) {
    __hip_bfloat162 h = __float22bfloat162_rn(make_float2(a, b));
    return *(uint32_t*)&h;
}

// 8 basis values (x6, since C carries the 1/6) for one x, packed bf16 into
// 16 bytes: 4 nonzero cubic weights shifted to slot j-3. h=0.4, g0=-2.2.
__device__ __forceinline__ uint4 bspline_pack(float xraw) {
    float e  = __expf(2.0f * xraw);
    float xn = 1.0f - 2.0f / (e + 1.0f);          // tanh; inf->1, 0->-1
    float u  = __fmaf_rn(xn, 2.5f, 5.5f);         // (xn + 2.2) / 0.4
    float fj = floorf(u);
    fj = fminf(fmaxf(fj, 3.0f), 7.0f);            // cell j in [3,7]
    float t  = u - fj;                            // [0,1]
    float omt = 1.0f - t;
    float t2 = t * t;
    float t3 = t2 * t;
    float w0 = omt * omt * omt;                   // x6 scaling folded into C
    float w3 = t3;
    float w1 = __fmaf_rn(3.0f, t3, __fmaf_rn(-6.0f, t2, 4.0f));
    float w2 = 6.0f - w0 - w1 - w3;               // partition of unity (x6)
    uint64_t packed = (uint64_t)pk2(w0, w1) | ((uint64_t)pk2(w2, w3) << 32);
    int sh = ((int)fj - 3) * 16;                  // 0,16,32,48,64 bits
    uint64_t lo, hi;
    if (sh == 0)      { lo = packed;       hi = 0ull; }
    else if (sh < 64) { lo = packed << sh; hi = packed >> (64 - sh); }
    else              { lo = 0ull;         hi = packed; }
    return make_uint4((uint32_t)lo, (uint32_t)(lo >> 32),
                      (uint32_t)hi, (uint32_t)(hi >> 32));
}

// C[i][o][k] fp32 * (1/6) -> BtT[i_blk][o][i_in*8+k] bf16. Coalesced both
// sides (R3 pattern: lane = o_off*8 + i_in).
__global__ __launch_bounds__(256)
void prep_bt(const float* __restrict__ C, unsigned short* __restrict__ BtT) {
    const float S = 1.0f / 6.0f;
    int g     = blockIdx.x * 256 + threadIdx.x;
    int lane  = g & 63;
    int w     = g >> 6;
    int i_in  = lane & 7;
    int o_off = lane >> 3;
    int i_blk = w & 63;
    int o     = ((w >> 6) << 3) + o_off;
    int i     = (i_blk << 3) + i_in;
    const float4* src = (const float4*)(C + ((size_t)i * OUT_F + o) * NB);
    float4 c0 = src[0];
    float4 c1 = src[1];
    uint4 val;
    val.x = pk2(c0.x * S, c0.y * S);
    val.y = pk2(c0.z * S, c0.w * S);
    val.z = pk2(c1.x * S, c1.y * S);
    val.w = pk2(c1.z * S, c1.w * S);
    *(uint4*)(BtT + (size_t)i_blk * CHUNK + o * 64 + i_in * 8) = val;
}

// 64x128 block tile, 4 waves each 64 rows x 32 cols (rm=4, cn=2 -> B has no
// intra-block duplication). A generated into XOR-swizzled dbuf LDS (1 barrier
// per 128-kk phase); B fragments register-dbuf'd one phase ahead; x two ahead.
__global__ __launch_bounds__(256)
void kan_gemm(const float* __restrict__ X, const unsigned short* __restrict__ BtT,
              float* __restrict__ Out) {
    __shared__ unsigned short As[2][BM * LROW];   // 2 x 32 KB

    const int tid    = threadIdx.x;
    const int lane   = tid & 63;
    const int wv     = tid >> 6;     // 0..3 column group
    const int lane16 = lane & 15;
    const int quad   = lane >> 4;

    const int row0 = blockIdx.y * BM;
    const int col0 = blockIdx.x * BN;
    const int C0   = wv * 32;

    f32x4 acc[4][2] = {};

    // pack mapping: gb = row in tile (0..63), i0 = first of 4 i's
    const int gb = tid >> 2;
    const int i0 = (tid & 3) * 4;
    const int sw = gb & 7;                        // XOR swizzle key (write)
    const int swr = lane16 & 7;                   // XOR swizzle key (read)
    const float4* xrow4 = (const float4*)(X + (size_t)(row0 + gb) * IN_F);

    // B fragment base: o = col0 + C0 + cn*16 + lane16
    const unsigned short* bbase =
        BtT + (size_t)(col0 + C0 + lane16) * 64 + quad * 8;

    s16x8 breg[2][2][4];   // [buf][cn][ks]

#define LOADB(buf_, ph_) do {                                                 \
    _Pragma("unroll") for (int cn = 0; cn < 2; ++cn)                          \
    _Pragma("unroll") for (int ks = 0; ks < 4; ++ks)                          \
        breg[buf_][cn][ks] = *(const s16x8*)(bbase                            \
            + (size_t)(2 * (ph_) + (ks >> 1)) * CHUNK                         \
            + cn * (16 * 64) + (ks & 1) * 32);                                \
} while (0)

#define PACK4(xv_, buf_) do {                                                 \
    uint4 p0 = bspline_pack((xv_).x);                                         \
    uint4 p1 = bspline_pack((xv_).y);                                         \
    uint4 p2 = bspline_pack((xv_).z);                                         \
    uint4 p3 = bspline_pack((xv_).w);                                         \
    unsigned short* wb = &As[buf_][gb * LROW];                                \
    *(uint4*)(wb + (((i0 + 0) ^ sw) << 3)) = p0;                              \
    *(uint4*)(wb + (((i0 + 1) ^ sw) << 3)) = p1;                              \
    *(uint4*)(wb + (((i0 + 2) ^ sw) << 3)) = p2;                              \
    *(uint4*)(wb + (((i0 + 3) ^ sw) << 3)) = p3;                              \
} while (0)

#define MFMASTEP(buf_) do {                                                   \
    _Pragma("unroll") for (int ks = 0; ks < 4; ++ks) {                        \
        s16x8 af[4];                                                          \
        _Pragma("unroll") for (int rm = 0; rm < 4; ++rm) {                    \
            const int r = rm * 16 + lane16;                                   \
            const int c = (ks * 4 + quad) ^ swr;                              \
            af[rm] = *(const s16x8*)&As[buf_][r * LROW + (c << 3)];           \
        }                                                                     \
        _Pragma("unroll") for (int rm = 0; rm < 4; ++rm)                      \
        _Pragma("unroll") for (int cn = 0; cn < 2; ++cn)                      \
            acc[rm][cn] = __builtin_amdgcn_mfma_f32_16x16x32_bf16(            \
                af[rm], breg[buf_][cn][ks], acc[rm][cn], 0, 0, 0);            \
    }                                                                         \
} while (0)

    // Prologue: x(0) -> pack tile 0 into As[0]; B(0) into breg[0]; x(1) early.
    {
        float4 x0 = xrow4[tid & 3];
        LOADB(0, 0);
        float4 x1 = xrow4[4 + (tid & 3)];
        PACK4(x0, 0);
        __syncthreads();

        float4 xnext = x1;   // x for phase ph+1's pack
        for (int ph = 0; ph < NPH; ++ph) {
            const int cur = ph & 1;
            if (ph + 1 < NPH) LOADB(cur ^ 1, ph + 1);   // B one phase ahead
            float4 xcur = xnext;
            if (ph + 2 < NPH)
                xnext = xrow4[(ph + 2) * 4 + (tid & 3)]; // x two phases ahead
            MFMASTEP(cur);                               // breg[cur]: arrived
            if (ph + 1 < NPH) PACK4(xcur, cur ^ 1);      // xcur: arrived
            __syncthreads();
        }
    }

    // Epilogue: C/D layout col=lane&15, row=quad*4+reg
    #pragma unroll
    for (int rm = 0; rm < 4; ++rm) {
        const int grow = row0 + rm * 16 + quad * 4;
        #pragma unroll
        for (int cn = 0; cn < 2; ++cn) {
            float* dst = Out + (size_t)grow * OUT_F + col0 + C0 + cn * 16 + lane16;
            #pragma unroll
            for (int r = 0; r < 4; ++r)
                dst[(size_t)r * OUT_F] = acc[rm][cn][r];
        }
    }
#undef LOADB
#undef PACK4
#undef MFMASTEP
}

extern "C" void kernel_launch(void* const* d_in, const int* in_sizes, int n_in,
                              void* d_out, int out_size, void* d_ws, size_t ws_size,
                              hipStream_t stream) {
    const float* X  = (const float*)d_in[0];   // (8192, 512) f32
    const float* C  = (const float*)d_in[1];   // (512, 512, 8) f32
    // d_in[2] = grid (uniform; constants hardcoded)
    float* Out = (float*)d_out;                // (8192, 512) f32
    unsigned short* BtT = (unsigned short*)d_ws;  // 4 MB bf16, CHUNK-tiled

    prep_bt<<<dim3(1024), 256, 0, stream>>>(C, BtT);
    kan_gemm<<<dim3(OUT_F / BN, BATCH / BM), 256, 0, stream>>>(X, BtT, Out);
}